// Round 5
// baseline (5253.762 us; speedup 1.0000x reference)
//
#include <hip/hip_runtime.h>
#include <hip/hip_bf16.h>
#include <stdint.h>

#define TT 4096
#define EE 256
#define LL 20
#define STARTT 18
#define STOPP 19
#define NEGV -10000.0f
#define NCH 256   // TT/16

typedef short v8s __attribute__((ext_vector_type(8)));
typedef float v4f __attribute__((ext_vector_type(4)));

// ---------- helpers ----------
__device__ inline float bf2f(unsigned short u){
  unsigned int x = ((unsigned int)u) << 16;
  return __builtin_bit_cast(float, x);
}
__device__ inline unsigned short f2bf(float f){
  unsigned int x = __builtin_bit_cast(unsigned int, f);
  unsigned int r = (x + 0x7FFFu + ((x >> 16) & 1u)) >> 16;
  return (unsigned short)r;
}
__device__ inline float bflo(unsigned int u){
  return __builtin_bit_cast(float, u << 16);
}
__device__ inline float bfhi(unsigned int u){
  return __builtin_bit_cast(float, u & 0xFFFF0000u);
}

#if __has_builtin(__builtin_amdgcn_sdot4)
#define SDOT4(a,b,c) __builtin_amdgcn_sdot4((int)(a),(int)(b),(c),false)
#else
__device__ inline int sdot4_sw(int a, int b, int c){
  return c + (int)(char)(a)        * (int)(char)(b)
           + (int)(char)(a >> 8)   * (int)(char)(b >> 8)
           + (int)(char)(a >> 16)  * (int)(char)(b >> 16)
           + (int)(char)(a >> 24)  * (int)(char)(b >> 24);
}
#define SDOT4(a,b,c) sdot4_sw((int)(a),(int)(b),(c))
#endif

__device__ inline float tanh_fast(float x){
  x = fminf(fmaxf(x, -20.f), 20.f);
  float e = __expf(-2.f * x);
  return (1.f - e) / (1.f + e);
}
__device__ inline float sigm(float x){
  return 1.f / (1.f + __expf(-x));
}

// lgkm-only barrier: syncs LDS without draining outstanding global (vmcnt) prefetch
#define BARRIER_LDS() asm volatile("s_waitcnt lgkmcnt(0)\ns_barrier" ::: "memory")

// ---------- workspace layout (bytes) ----------
constexpr size_t OFF_U    = 0;                              // bf16 [2][T][256][4]
constexpr size_t SZ_U     = 2ull*TT*1024*2;
constexpr size_t OFF_X    = OFF_U + SZ_U;                   // bf16 [T][E]
constexpr size_t SZ_X     = (size_t)TT*EE*2;
constexpr size_t OFF_WIH  = OFF_X + SZ_X;                   // bf16 [2048][256]
constexpr size_t SZ_WIH   = 2048ull*256*2;
constexpr size_t OFF_BIAS = OFF_WIH + SZ_WIH;               // f32 [2048]
constexpr size_t SZ_BIAS  = 2048ull*4;
constexpr size_t OFF_WQ   = OFF_BIAS + SZ_BIAS;             // uint4 [2][32][512] (i8 packed)
constexpr size_t SZ_WQ    = 2ull*32*512*16;
constexpr size_t OFF_FS   = OFF_WQ + SZ_WQ;                 // f32 [2][4][256]
constexpr size_t SZ_FS    = 2ull*4*256*4;
constexpr size_t OFF_WOP  = OFF_FS + SZ_FS;                 // bf16 [32][512]
constexpr size_t SZ_WOP   = 32ull*512*2;
constexpr size_t OFF_HOUT = OFF_WOP + SZ_WOP;               // bf16 [T][512]
constexpr size_t SZ_HOUT  = (size_t)TT*512*2;
constexpr size_t OFF_FE   = OFF_HOUT + SZ_HOUT;             // f32 [T][20]
constexpr size_t SZ_FE    = (size_t)TT*LL*4;
constexpr size_t OFF_P    = OFF_FE + SZ_FE;                 // f32 [256][20][20]
constexpr size_t SZ_P     = 256ull*400*4;
constexpr size_t OFF_BAL  = OFF_P + SZ_P;                   // f32 [257][20]
constexpr size_t SZ_BAL   = 20736;
constexpr size_t OFF_BP   = OFF_BAL + SZ_BAL;               // u8 [T][20]
constexpr size_t SZ_BP    = (size_t)TT*LL;
constexpr size_t OFF_M    = OFF_BP + SZ_BP;                 // u8 [256][20]
constexpr size_t SZ_M     = 256ull*LL;
constexpr size_t OFF_EG   = OFF_M + SZ_M + 64;              // i32 [256]

// ---------- prep kernels ----------

__global__ void k_gather(const int* __restrict__ x, const float* __restrict__ emb,
                         unsigned short* __restrict__ X){
  int t = blockIdx.x;
  int xt = x[t];
  const float4* src = (const float4*)(emb + (size_t)xt * EE);
  float4 v = src[threadIdx.x];
  ushort4 o;
  o.x = f2bf(v.x); o.y = f2bf(v.y); o.z = f2bf(v.z); o.w = f2bf(v.w);
  ((ushort4*)(X + (size_t)t * EE))[threadIdx.x] = o;
}

__global__ void k_wih(const float* __restrict__ wf, const float* __restrict__ wb,
                      unsigned short* __restrict__ WIH){
  int gid = blockIdx.x * 256 + threadIdx.x;   // 65536
  int row = gid >> 5, c8 = gid & 31;
  const float* src = (row < 1024 ? wf + (size_t)row * EE : wb + (size_t)(row - 1024) * EE) + c8 * 8;
  unsigned short* dst = WIH + (size_t)row * 256 + c8 * 8;
#pragma unroll
  for (int i = 0; i < 8; i++) dst[i] = f2bf(src[i]);
}

__global__ void k_bias(const float* bf, const float* hf, const float* bb, const float* hb,
                       float* __restrict__ bias){
  int i = blockIdx.x * 256 + threadIdx.x;     // 2048
  int r = i & 1023;
  bias[i] = (i < 1024) ? (bf[r] + hf[r]) : (bb[r] + hb[r]);
}

// w_out -> bf16, padded to 32 rows
__global__ void k_wout(const float* __restrict__ wout, unsigned short* __restrict__ WOP){
  int gid = blockIdx.x * 256 + threadIdx.x;   // 16384 = 32*512
  int row = gid >> 9, k = gid & 511;
  WOP[gid] = (row < LL) ? f2bf(wout[row * 512 + k]) : 0;
}

// quantize W_hh rows to int8 with per-row scale.
__global__ void k_whh4(const float* __restrict__ whf, const float* __restrict__ whb,
                       unsigned int* __restrict__ WQ, float* __restrict__ FS){
  int row = blockIdx.x;       // 0..2047
  int d = row >> 10, R = row & 1023;
  int g = R >> 8, j = R & 255;
  const float* W = (d ? whb : whf) + (size_t)R * 256;
  int t = threadIdx.x;        // 0..63 ; covers cols 4t..4t+3
  float4 v = ((const float4*)W)[t];
  float m = fmaxf(fmaxf(fabsf(v.x), fabsf(v.y)), fmaxf(fabsf(v.z), fabsf(v.w)));
#pragma unroll
  for (int o = 32; o >= 1; o >>= 1) m = fmaxf(m, __shfl_down(m, o));
  m = __shfl(m, 0);
  float sc = (m > 0.f) ? (m / 127.f) : 1.f;
  float inv = 1.f / sc;
  int a = (int)rintf(v.x * inv), b = (int)rintf(v.y * inv);
  int c = (int)rintf(v.z * inv), e = (int)rintf(v.w * inv);
  unsigned int pack = ((unsigned)a & 255u) | (((unsigned)b & 255u) << 8)
                    | (((unsigned)c & 255u) << 16) | (((unsigned)e & 255u) << 24);
  int kh = t >> 5;
  int q  = (t & 31) >> 2;
  int comp = t & 3;
  WQ[(((size_t)(d * 32 + g * 8 + q)) * 512 + kh * 256 + j) * 4 + comp] = pack;
  if (t == 0) FS[(d * 4 + g) * 256 + j] = sc;
}

// U[d][t][j][g] = bf16( X[t]·W_ih row (g*256+j) + bias )  via 16x16x32 bf16 MFMA
__global__ void k_gemm_u(const unsigned short* __restrict__ X,
                         const unsigned short* __restrict__ WIH,
                         const float* __restrict__ bias,
                         unsigned short* __restrict__ U){
  int wave = threadIdx.x >> 6, l = threadIdx.x & 63;
  int tile = blockIdx.x * 4 + wave;           // 0..32767
  int mt = tile & 255, nt = tile >> 8;        // 256 x 128 tiles
  int lm = l & 15, lq = l >> 4;
  const unsigned short* Arow = X   + (size_t)(mt * 16 + lm) * 256 + lq * 8;
  const unsigned short* Brow = WIH + (size_t)(nt * 16 + lm) * 256 + lq * 8;
  v4f acc = {0.f, 0.f, 0.f, 0.f};
#pragma unroll
  for (int kb = 0; kb < 8; kb++){
    v8s a = *(const v8s*)(Arow + kb * 32);
    v8s b = *(const v8s*)(Brow + kb * 32);
    acc = __builtin_amdgcn_mfma_f32_16x16x32_bf16(a, b, acc, 0, 0, 0);
  }
  int n = nt * 16 + lm;                       // 0..2047 gate-row
  int dd = n >> 10, r = n & 1023;
  int jj = r & 255, gg = r >> 8;
  float bi = bias[n];
#pragma unroll
  for (int r4 = 0; r4 < 4; r4++){
    int t = mt * 16 + lq * 4 + r4;
    U[(((size_t)(dd * TT + t)) * 256 + jj) * 4 + gg] = f2bf(acc[r4] + bi);
  }
}

// ---------- the recurrent core ----------
// grid=2 (one CU per direction), block=512 (8 waves = 2/SIMD).
// thread t: element j=t&255, K-half kh=t>>8. Owns all 4 gate rows of j over
// its K-half: 128 scalar u32 of packed i8 weights, PINNED in VGPRs by inline
// asm so the compiler cannot sink the loads into the loop (R2/R3 failure mode).

#define WGQ(M) \
  M(0,0) M(0,1) M(0,2) M(0,3) M(0,4) M(0,5) M(0,6) M(0,7) \
  M(1,0) M(1,1) M(1,2) M(1,3) M(1,4) M(1,5) M(1,6) M(1,7) \
  M(2,0) M(2,1) M(2,2) M(2,3) M(2,4) M(2,5) M(2,6) M(2,7) \
  M(3,0) M(3,1) M(3,2) M(3,3) M(3,4) M(3,5) M(3,6) M(3,7)

#define H8(M) M(0) M(1) M(2) M(3) M(4) M(5) M(6) M(7)

#define DECLW(g,q) unsigned wx_##g##_##q, wy_##g##_##q, wz_##g##_##q, ww_##g##_##q;
#define LOADW(g,q) { uint4 _tw = WQ4[base4 + ((g)*8+(q))*512]; \
                     wx_##g##_##q = _tw.x; wy_##g##_##q = _tw.y; \
                     wz_##g##_##q = _tw.z; ww_##g##_##q = _tw.w; }
#define PINW(g,q) asm volatile("" : "+v"(wx_##g##_##q), "+v"(wy_##g##_##q), \
                                    "+v"(wz_##g##_##q), "+v"(ww_##g##_##q));
#define DECLH(q)   uint4 h_##q;
#define LOADH(q)   h_##q = hq[q];
#define DOTC(g,q,comp) a##g = SDOT4(w##comp##_##g##_##q, h_##q.comp, a##g);
#define DOTQ(q) DOTC(0,q,x) DOTC(1,q,x) DOTC(2,q,x) DOTC(3,q,x) \
                DOTC(0,q,y) DOTC(1,q,y) DOTC(2,q,y) DOTC(3,q,y) \
                DOTC(0,q,z) DOTC(1,q,z) DOTC(2,q,z) DOTC(3,q,z) \
                DOTC(0,q,w) DOTC(1,q,w) DOTC(2,q,w) DOTC(3,q,w)

__global__ __launch_bounds__(512, 2) void k_lstm5(
    const unsigned short* __restrict__ U, const uint4* __restrict__ WQ4,
    const float* __restrict__ FS, const float* __restrict__ h0,
    const float* __restrict__ c0, unsigned short* __restrict__ hout){
  int d = blockIdx.x;
  int t = threadIdx.x;
  int j = t & 255, kh = t >> 8;

  __shared__ __align__(16) unsigned char hb[2][256];
  __shared__ __align__(16) float4 zl[512];

  WGQ(DECLW)
  {
    size_t base4 = (size_t)d * 32 * 512 + t;
    WGQ(LOADW)
  }
  WGQ(PINW)          // weights are now opaque register values — cannot be re-loaded

  float fs0 = FS[(d * 4 + 0) * 256 + j];
  float fs1 = FS[(d * 4 + 1) * 256 + j];
  float fs2 = FS[(d * 4 + 2) * 256 + j];
  float fs3 = FS[(d * 4 + 3) * 256 + j];

  float cst = 0.f;
  const uint2* U2 = (const uint2*)U;
  size_t ub = (size_t)d * TT * 256 + j;
  int stp = d ? -1 : 1;
  uint2 u_c = {0u, 0u}, u_n = {0u, 0u};
  if (t < 256){
    cst = c0[d * 256 + j];
    float hini = h0[d * 256 + j];
    hini = fminf(fmaxf(hini, -8.f), 8.f);
    hb[0][j] = (unsigned char)(char)(int)rintf(hini * (127.f / 8.f));
    int tA = d ? TT - 1 : 0;
    u_c = U2[ub + (size_t)tA * 256];
    u_n = U2[ub + (size_t)(tA + stp) * 256];
  }
  float hs = 8.f / 127.f;                // h-quant scale (step 0: h0 range ±8)
  __syncthreads();

  for (int s = 0; s < TT; s++){
    int par = s & 1;
    const uint4* hq = (const uint4*)(&hb[par][kh * 128]);
    H8(DECLH)
    H8(LOADH)

    int a0 = 0, a1 = 0, a2 = 0, a3 = 0;
    H8(DOTQ)                            // 128 x v_dot4_i32_i8, 4-way ILP

    float m0 = fs0 * hs, m1 = fs1 * hs, m2 = fs2 * hs, m3 = fs3 * hs;
    float4 zp;
    zp.x = (float)a0 * m0; zp.y = (float)a1 * m1;
    zp.z = (float)a2 * m2; zp.w = (float)a3 * m3;
    zl[t] = zp;
    BARRIER_LDS();

    if (t < 256){
      int tt = d ? (TT - 1 - s) : s;
      float4 zq = zl[t + 256];
      float zi = bflo(u_c.x) + zp.x + zq.x;
      float zf = bfhi(u_c.x) + zp.y + zq.y;
      float zg = bflo(u_c.y) + zp.z + zq.z;
      float zo = bfhi(u_c.y) + zp.w + zq.w;
      float gi = sigm(zi), gf = sigm(zf), go = sigm(zo), gg = tanh_fast(zg);
      cst = gf * cst + gi * gg;
      float h = go * tanh_fast(cst);
      hout[(size_t)tt * 512 + d * 256 + j] = f2bf(h);
      int q = (int)rintf(fminf(fmaxf(h, -1.f), 1.f) * 127.f);
      hb[par ^ 1][j] = (unsigned char)(char)q;
      u_c = u_n;
      int t2 = tt + 2 * stp;
      if (t2 >= 0 && t2 < TT) u_n = U2[ub + (size_t)t2 * 256];
    }
    hs = 1.f / 127.f;                   // steps >=1: h in (-1,1)
    BARRIER_LDS();
  }
}

// feats via MFMA: FE[t][j] = HOUT[t]·WOP[j] + bout[j], WOP padded to 32 rows
__global__ void k_feats2(const unsigned short* __restrict__ HOUT,
                         const unsigned short* __restrict__ WOP,
                         const float* __restrict__ bout,
                         float* __restrict__ feats){
  int wave = threadIdx.x >> 6, l = threadIdx.x & 63;
  int tile = blockIdx.x * 4 + wave;           // 0..511
  int mt = tile & 255, nt = tile >> 8;        // 256 M-tiles x 2 N-tiles
  int lm = l & 15, lq = l >> 4;
  const unsigned short* Arow = HOUT + (size_t)(mt * 16 + lm) * 512 + lq * 8;
  const unsigned short* Brow = WOP  + (size_t)(nt * 16 + lm) * 512 + lq * 8;
  v4f acc = {0.f, 0.f, 0.f, 0.f};
#pragma unroll
  for (int kb = 0; kb < 16; kb++){
    v8s a = *(const v8s*)(Arow + kb * 32);
    v8s b = *(const v8s*)(Brow + kb * 32);
    acc = __builtin_amdgcn_mfma_f32_16x16x32_bf16(a, b, acc, 0, 0, 0);
  }
  int n = nt * 16 + lm;
  if (n < LL){
    float bi = bout[n];
#pragma unroll
    for (int r4 = 0; r4 < 4; r4++){
      int t = mt * 16 + lq * 4 + r4;
      feats[t * LL + n] = acc[r4] + bi;
    }
  }
}

// V1: per-chunk max-plus matrix product
__global__ void k_vchunk(const float* __restrict__ feats, const float* __restrict__ trans,
                         float* __restrict__ P){
  int c = blockIdx.x, j = threadIdx.x;
  __shared__ float Ps[2][LL][LL];
  bool act = j < LL;
  float trow[LL];
  if (act){
#pragma unroll
    for (int i = 0; i < LL; i++) trow[i] = trans[j * LL + i];
    for (int i = 0; i < LL; i++) Ps[0][i][j] = (i == j) ? 0.f : -1e30f;
  }
  __syncthreads();
  for (int s = 0; s < 16; s++){
    int t = c * 16 + s;
    int pb = s & 1;
    if (act){
      float fj = feats[t * LL + j];
      for (int i = 0; i < LL; i++){
        float m = Ps[pb][i][0] + trow[0];
#pragma unroll
        for (int mm = 1; mm < LL; mm++) m = fmaxf(m, Ps[pb][i][mm] + trow[mm]);
        Ps[pb ^ 1][i][j] = m + fj;
      }
    }
    __syncthreads();
  }
  if (act)
    for (int i = 0; i < LL; i++) P[((size_t)c * LL + i) * LL + j] = Ps[0][i][j];
}

// V2: sequential boundary-alpha scan (prefetch-pipelined)
__global__ void k_vscan(const float* __restrict__ P, float* __restrict__ bal){
  int tid = threadIdx.x;
  bool act = tid < LL;
  __shared__ float al[LL];
  __shared__ float Pl[400];
  if (act){
    float a = (tid == STARTT) ? 0.f : NEGV;
    al[tid] = a;
    bal[tid] = a;
  }
  for (int k = tid; k < 400; k += 64) Pl[k] = P[k];
  __syncthreads();
  for (int c = 0; c < NCH; c++){
    float p0 = 0.f, p1 = 0.f, p2 = 0.f, p3 = 0.f, p4 = 0.f, p5 = 0.f, p6 = 0.f;
    if (c + 1 < NCH){
      const float* Pn = P + (size_t)(c + 1) * 400;
      p0 = Pn[tid];        p1 = Pn[tid + 64];  p2 = Pn[tid + 128];
      p3 = Pn[tid + 192];  p4 = Pn[tid + 256]; p5 = Pn[tid + 320];
      if (tid + 384 < 400) p6 = Pn[tid + 384];
    }
    float m = -1e30f;
    if (act){
      m = al[0] + Pl[tid];
#pragma unroll
      for (int i = 1; i < LL; i++) m = fmaxf(m, al[i] + Pl[i * LL + tid]);
    }
    __syncthreads();
    if (act){
      al[tid] = m;
      bal[(c + 1) * LL + tid] = m;
    }
    if (c + 1 < NCH){
      Pl[tid] = p0;        Pl[tid + 64] = p1;  Pl[tid + 128] = p2;
      Pl[tid + 192] = p3;  Pl[tid + 256] = p4; Pl[tid + 320] = p5;
      if (tid + 384 < 400) Pl[tid + 384] = p6;
    }
    __syncthreads();
  }
}

// V3: per-chunk backpointers + chunk backtrace map
__global__ void k_vbp(const float* __restrict__ feats, const float* __restrict__ trans,
                      const float* __restrict__ bal, unsigned char* __restrict__ bp,
                      unsigned char* __restrict__ M){
  int c = blockIdx.x, j = threadIdx.x;
  bool act = j < LL;
  __shared__ float al[2][LL];
  __shared__ unsigned char bpl[16][LL];
  float trow[LL];
  if (act){
#pragma unroll
    for (int i = 0; i < LL; i++) trow[i] = trans[j * LL + i];
    al[0][j] = bal[c * LL + j];
  }
  __syncthreads();
  for (int s = 0; s < 16; s++){
    int t = c * 16 + s;
    int pb = s & 1;
    if (act){
      float m = al[pb][0] + trow[0];
      int arg = 0;
#pragma unroll
      for (int i = 1; i < LL; i++){
        float v = al[pb][i] + trow[i];
        if (v > m){ m = v; arg = i; }
      }
      bpl[s][j] = (unsigned char)arg;
      bp[(size_t)t * LL + j] = (unsigned char)arg;
      al[pb ^ 1][j] = m + feats[t * LL + j];
    }
    __syncthreads();
  }
  if (act){
    int tag = j;
    for (int s = 15; s >= 0; s--) tag = bpl[s][tag];
    M[c * LL + j] = (unsigned char)tag;
  }
}

// V4: final score + chunk-boundary tag chase
__global__ void k_vtag(const float* __restrict__ bal, const float* __restrict__ trans,
                       const unsigned char* __restrict__ M, int* __restrict__ Eg,
                       float* __restrict__ out){
  int tid = threadIdx.x;
  __shared__ unsigned char Ml[NCH * LL];
  __shared__ float fin[LL];
  for (int k = tid; k < NCH * LL; k += 64) Ml[k] = M[k];
  if (tid < LL) fin[tid] = bal[NCH * LL + tid] + trans[STOPP * LL + tid];
  __syncthreads();
  if (tid == 0){
    float m = fin[0]; int arg = 0;
    for (int i = 1; i < LL; i++) if (fin[i] > m){ m = fin[i]; arg = i; }
    out[0] = m;
    int tag = arg;
    Eg[NCH - 1] = tag;
    for (int c = NCH - 1; c >= 1; c--){
      tag = Ml[c * LL + tag];
      Eg[c - 1] = tag;
    }
  }
}

// V5: parallel path emission
__global__ void k_vemit(const int* __restrict__ Eg, const unsigned char* __restrict__ bp,
                        float* __restrict__ out){
  int c = threadIdx.x;
  int tag = Eg[c];
  out[1 + c * 16 + 15] = (float)tag;
  for (int s = 15; s >= 1; s--){
    tag = bp[(size_t)(c * 16 + s) * LL + tag];
    out[1 + c * 16 + s - 1] = (float)tag;
  }
}

// ---------- launcher ----------
extern "C" void kernel_launch(void* const* d_in, const int* in_sizes, int n_in,
                              void* d_out, int out_size, void* d_ws, size_t ws_size,
                              hipStream_t stream){
  (void)in_sizes; (void)n_in; (void)out_size; (void)ws_size;
  const int*   x     = (const int*)d_in[0];
  const float* emb   = (const float*)d_in[1];
  const float* wihf  = (const float*)d_in[2];
  const float* whhf  = (const float*)d_in[3];
  const float* bihf  = (const float*)d_in[4];
  const float* bhhf  = (const float*)d_in[5];
  const float* wihb  = (const float*)d_in[6];
  const float* whhb  = (const float*)d_in[7];
  const float* bihb  = (const float*)d_in[8];
  const float* bhhb  = (const float*)d_in[9];
  const float* wout  = (const float*)d_in[10];
  const float* bout  = (const float*)d_in[11];
  const float* trans = (const float*)d_in[12];
  const float* h0    = (const float*)d_in[13];
  const float* c0    = (const float*)d_in[14];
  float* out = (float*)d_out;
  char* ws = (char*)d_ws;

  unsigned short* U    = (unsigned short*)(ws + OFF_U);
  unsigned short* X    = (unsigned short*)(ws + OFF_X);
  unsigned short* WIH  = (unsigned short*)(ws + OFF_WIH);
  float*          BIAS = (float*)(ws + OFF_BIAS);
  unsigned int*   WQ   = (unsigned int*)(ws + OFF_WQ);
  float*          FS   = (float*)(ws + OFF_FS);
  unsigned short* WOP  = (unsigned short*)(ws + OFF_WOP);
  unsigned short* HOUT = (unsigned short*)(ws + OFF_HOUT);
  float*          FE   = (float*)(ws + OFF_FE);
  float*          P    = (float*)(ws + OFF_P);
  float*          BAL  = (float*)(ws + OFF_BAL);
  unsigned char*  BP   = (unsigned char*)(ws + OFF_BP);
  unsigned char*  M    = (unsigned char*)(ws + OFF_M);
  int*            EG   = (int*)(ws + OFF_EG);

  k_gather<<<TT, 64, 0, stream>>>(x, emb, X);
  k_wih<<<256, 256, 0, stream>>>(wihf, wihb, WIH);
  k_bias<<<8, 256, 0, stream>>>(bihf, bhhf, bihb, bhhb, BIAS);
  k_wout<<<64, 256, 0, stream>>>(wout, WOP);
  k_whh4<<<2048, 64, 0, stream>>>(whhf, whhb, WQ, FS);
  k_gemm_u<<<8192, 256, 0, stream>>>(X, WIH, BIAS, U);
  k_lstm5<<<2, 512, 0, stream>>>(U, (const uint4*)WQ, FS, h0, c0, HOUT);
  k_feats2<<<128, 256, 0, stream>>>(HOUT, WOP, bout, FE);
  k_vchunk<<<NCH, 64, 0, stream>>>(FE, trans, P);
  k_vscan<<<1, 64, 0, stream>>>(P, BAL);
  k_vbp<<<NCH, 64, 0, stream>>>(FE, trans, BAL, BP, M);
  k_vtag<<<1, 64, 0, stream>>>(BAL, trans, M, EG, out);
  k_vemit<<<1, 256, 0, stream>>>(EG, BP, out);
}

// Round 6
// 4927.810 us; speedup vs baseline: 1.0661x; 1.0661x over previous
//
#include <hip/hip_runtime.h>
#include <hip/hip_bf16.h>
#include <stdint.h>

#define TT 4096
#define EE 256
#define LL 20
#define STARTT 18
#define STOPP 19
#define NEGV -10000.0f
#define NCH 256   // TT/16

typedef short v8s __attribute__((ext_vector_type(8)));
typedef float v4f __attribute__((ext_vector_type(4)));

// ---------- helpers ----------
__device__ inline float bf2f(unsigned short u){
  unsigned int x = ((unsigned int)u) << 16;
  return __builtin_bit_cast(float, x);
}
__device__ inline unsigned short f2bf(float f){
  unsigned int x = __builtin_bit_cast(unsigned int, f);
  unsigned int r = (x + 0x7FFFu + ((x >> 16) & 1u)) >> 16;
  return (unsigned short)r;
}
__device__ inline float bflo(unsigned int u){
  return __builtin_bit_cast(float, u << 16);
}
__device__ inline float bfhi(unsigned int u){
  return __builtin_bit_cast(float, u & 0xFFFF0000u);
}

#if __has_builtin(__builtin_amdgcn_sdot4)
#define SDOT4(a,b,c) __builtin_amdgcn_sdot4((int)(a),(int)(b),(c),false)
#else
__device__ inline int sdot4_sw(int a, int b, int c){
  return c + (int)(char)(a)        * (int)(char)(b)
           + (int)(char)(a >> 8)   * (int)(char)(b >> 8)
           + (int)(char)(a >> 16)  * (int)(char)(b >> 16)
           + (int)(char)(a >> 24)  * (int)(char)(b >> 24);
}
#define SDOT4(a,b,c) sdot4_sw((int)(a),(int)(b),(c))
#endif

__device__ inline float tanh_fast(float x){
  x = fminf(fmaxf(x, -20.f), 20.f);
  float e = __expf(-2.f * x);
  return (1.f - e) / (1.f + e);
}
__device__ inline float sigm(float x){
  return 1.f / (1.f + __expf(-x));
}

// lgkm-only barrier: syncs LDS without draining outstanding global (vmcnt) prefetch
#define BARRIER_LDS() asm volatile("s_waitcnt lgkmcnt(0)\ns_barrier" ::: "memory")

// ---------- workspace layout (bytes) ----------
constexpr size_t OFF_U    = 0;                              // bf16 [2][T][256][4]
constexpr size_t SZ_U     = 2ull*TT*1024*2;
constexpr size_t OFF_X    = OFF_U + SZ_U;                   // bf16 [T][E]
constexpr size_t SZ_X     = (size_t)TT*EE*2;
constexpr size_t OFF_WIH  = OFF_X + SZ_X;                   // bf16 [2048][256]
constexpr size_t SZ_WIH   = 2048ull*256*2;
constexpr size_t OFF_BIAS = OFF_WIH + SZ_WIH;               // f32 [2048]
constexpr size_t SZ_BIAS  = 2048ull*4;
constexpr size_t OFF_WQ   = OFF_BIAS + SZ_BIAS;             // uint4 [2][32][512] (i8 packed)
constexpr size_t SZ_WQ    = 2ull*32*512*16;
constexpr size_t OFF_FS   = OFF_WQ + SZ_WQ;                 // f32 [2][4][256]
constexpr size_t SZ_FS    = 2ull*4*256*4;
constexpr size_t OFF_WOP  = OFF_FS + SZ_FS;                 // bf16 [32][512]
constexpr size_t SZ_WOP   = 32ull*512*2;
constexpr size_t OFF_HOUT = OFF_WOP + SZ_WOP;               // bf16 [T][512]
constexpr size_t SZ_HOUT  = (size_t)TT*512*2;
constexpr size_t OFF_FE   = OFF_HOUT + SZ_HOUT;             // f32 [T][20]
constexpr size_t SZ_FE    = (size_t)TT*LL*4;
constexpr size_t OFF_P    = OFF_FE + SZ_FE;                 // f32 [256][20][20]
constexpr size_t SZ_P     = 256ull*400*4;
constexpr size_t OFF_BAL  = OFF_P + SZ_P;                   // f32 [257][20]
constexpr size_t SZ_BAL   = 20736;
constexpr size_t OFF_BP   = OFF_BAL + SZ_BAL;               // u8 [T][20]
constexpr size_t SZ_BP    = (size_t)TT*LL;
constexpr size_t OFF_M    = OFF_BP + SZ_BP;                 // u8 [256][20]
constexpr size_t SZ_M     = 256ull*LL;
constexpr size_t OFF_EG   = OFF_M + SZ_M + 64;              // i32 [256]

// ---------- prep kernels ----------

__global__ void k_gather(const int* __restrict__ x, const float* __restrict__ emb,
                         unsigned short* __restrict__ X){
  int t = blockIdx.x;
  int xt = x[t];
  const float4* src = (const float4*)(emb + (size_t)xt * EE);
  float4 v = src[threadIdx.x];
  ushort4 o;
  o.x = f2bf(v.x); o.y = f2bf(v.y); o.z = f2bf(v.z); o.w = f2bf(v.w);
  ((ushort4*)(X + (size_t)t * EE))[threadIdx.x] = o;
}

__global__ void k_wih(const float* __restrict__ wf, const float* __restrict__ wb,
                      unsigned short* __restrict__ WIH){
  int gid = blockIdx.x * 256 + threadIdx.x;   // 65536
  int row = gid >> 5, c8 = gid & 31;
  const float* src = (row < 1024 ? wf + (size_t)row * EE : wb + (size_t)(row - 1024) * EE) + c8 * 8;
  unsigned short* dst = WIH + (size_t)row * 256 + c8 * 8;
#pragma unroll
  for (int i = 0; i < 8; i++) dst[i] = f2bf(src[i]);
}

__global__ void k_bias(const float* bf, const float* hf, const float* bb, const float* hb,
                       float* __restrict__ bias){
  int i = blockIdx.x * 256 + threadIdx.x;     // 2048
  int r = i & 1023;
  bias[i] = (i < 1024) ? (bf[r] + hf[r]) : (bb[r] + hb[r]);
}

// w_out -> bf16, padded to 32 rows
__global__ void k_wout(const float* __restrict__ wout, unsigned short* __restrict__ WOP){
  int gid = blockIdx.x * 256 + threadIdx.x;   // 16384 = 32*512
  int row = gid >> 9, k = gid & 511;
  WOP[gid] = (row < LL) ? f2bf(wout[row * 512 + k]) : 0;
}

// quantize W_hh rows to int8 with per-row scale.
__global__ void k_whh4(const float* __restrict__ whf, const float* __restrict__ whb,
                       unsigned int* __restrict__ WQ, float* __restrict__ FS){
  int row = blockIdx.x;       // 0..2047
  int d = row >> 10, R = row & 1023;
  int g = R >> 8, j = R & 255;
  const float* W = (d ? whb : whf) + (size_t)R * 256;
  int t = threadIdx.x;        // 0..63 ; covers cols 4t..4t+3
  float4 v = ((const float4*)W)[t];
  float m = fmaxf(fmaxf(fabsf(v.x), fabsf(v.y)), fmaxf(fabsf(v.z), fabsf(v.w)));
#pragma unroll
  for (int o = 32; o >= 1; o >>= 1) m = fmaxf(m, __shfl_down(m, o));
  m = __shfl(m, 0);
  float sc = (m > 0.f) ? (m / 127.f) : 1.f;
  float inv = 1.f / sc;
  int a = (int)rintf(v.x * inv), b = (int)rintf(v.y * inv);
  int c = (int)rintf(v.z * inv), e = (int)rintf(v.w * inv);
  unsigned int pack = ((unsigned)a & 255u) | (((unsigned)b & 255u) << 8)
                    | (((unsigned)c & 255u) << 16) | (((unsigned)e & 255u) << 24);
  int kh = t >> 5;
  int q  = (t & 31) >> 2;
  int comp = t & 3;
  WQ[(((size_t)(d * 32 + g * 8 + q)) * 512 + kh * 256 + j) * 4 + comp] = pack;
  if (t == 0) FS[(d * 4 + g) * 256 + j] = sc;
}

// U[d][t][j][g] = bf16( X[t]·W_ih row (g*256+j) + bias )  via 16x16x32 bf16 MFMA
__global__ void k_gemm_u(const unsigned short* __restrict__ X,
                         const unsigned short* __restrict__ WIH,
                         const float* __restrict__ bias,
                         unsigned short* __restrict__ U){
  int wave = threadIdx.x >> 6, l = threadIdx.x & 63;
  int tile = blockIdx.x * 4 + wave;           // 0..32767
  int mt = tile & 255, nt = tile >> 8;        // 256 x 128 tiles
  int lm = l & 15, lq = l >> 4;
  const unsigned short* Arow = X   + (size_t)(mt * 16 + lm) * 256 + lq * 8;
  const unsigned short* Brow = WIH + (size_t)(nt * 16 + lm) * 256 + lq * 8;
  v4f acc = {0.f, 0.f, 0.f, 0.f};
#pragma unroll
  for (int kb = 0; kb < 8; kb++){
    v8s a = *(const v8s*)(Arow + kb * 32);
    v8s b = *(const v8s*)(Brow + kb * 32);
    acc = __builtin_amdgcn_mfma_f32_16x16x32_bf16(a, b, acc, 0, 0, 0);
  }
  int n = nt * 16 + lm;                       // 0..2047 gate-row
  int dd = n >> 10, r = n & 1023;
  int jj = r & 255, gg = r >> 8;
  float bi = bias[n];
#pragma unroll
  for (int r4 = 0; r4 < 4; r4++){
    int t = mt * 16 + lq * 4 + r4;
    U[(((size_t)(dd * TT + t)) * 256 + jj) * 4 + gg] = f2bf(acc[r4] + bi);
  }
}

// ---------- the recurrent core ----------
// grid=2 (one CU per direction), block=512 (8 waves = 2/SIMD).
// thread t: element j=t&255, K-half kh=t>>8. Owns all 4 gate rows of j over
// its K-half: 128 u32 of packed i8 weights, pinned in VGPRs via inline asm.
// amdgpu_waves_per_eu(2,2) clamps the occupancy target so the register
// allocator gets the full 256-VGPR budget (R4 failure: RA targeted ~6
// waves/EU and spilled the pinned weights to scratch).

#define WGQ(M) \
  M(0,0) M(0,1) M(0,2) M(0,3) M(0,4) M(0,5) M(0,6) M(0,7) \
  M(1,0) M(1,1) M(1,2) M(1,3) M(1,4) M(1,5) M(1,6) M(1,7) \
  M(2,0) M(2,1) M(2,2) M(2,3) M(2,4) M(2,5) M(2,6) M(2,7) \
  M(3,0) M(3,1) M(3,2) M(3,3) M(3,4) M(3,5) M(3,6) M(3,7)

#define H8(M) M(0) M(1) M(2) M(3) M(4) M(5) M(6) M(7)

#define DECLW(g,q) unsigned wx_##g##_##q, wy_##g##_##q, wz_##g##_##q, ww_##g##_##q;
#define LOADW(g,q) { uint4 _tw = WQ4[base4 + ((g)*8+(q))*512]; \
                     wx_##g##_##q = _tw.x; wy_##g##_##q = _tw.y; \
                     wz_##g##_##q = _tw.z; ww_##g##_##q = _tw.w; }
#define PINW(g,q) asm volatile("" : "+v"(wx_##g##_##q), "+v"(wy_##g##_##q), \
                                    "+v"(wz_##g##_##q), "+v"(ww_##g##_##q));
#define DECLH(q)   uint4 h_##q;
#define LOADH(q)   h_##q = hq[q];
#define DOTC(g,q,comp) a##g = SDOT4(w##comp##_##g##_##q, h_##q.comp, a##g);
#define DOTQ(q) DOTC(0,q,x) DOTC(1,q,x) DOTC(2,q,x) DOTC(3,q,x) \
                DOTC(0,q,y) DOTC(1,q,y) DOTC(2,q,y) DOTC(3,q,y) \
                DOTC(0,q,z) DOTC(1,q,z) DOTC(2,q,z) DOTC(3,q,z) \
                DOTC(0,q,w) DOTC(1,q,w) DOTC(2,q,w) DOTC(3,q,w)

__global__ void __launch_bounds__(512)
__attribute__((amdgpu_waves_per_eu(2, 2)))
k_lstm6(
    const unsigned short* __restrict__ U, const uint4* __restrict__ WQ4,
    const float* __restrict__ FS, const float* __restrict__ h0,
    const float* __restrict__ c0, unsigned short* __restrict__ hout){
  int d = blockIdx.x;
  int t = threadIdx.x;
  int j = t & 255, kh = t >> 8;

  __shared__ __align__(16) unsigned char hb[2][256];
  __shared__ __align__(16) float4 zl[512];

  WGQ(DECLW)
  {
    size_t base4 = (size_t)d * 32 * 512 + t;
    WGQ(LOADW)
  }
  WGQ(PINW)          // weights are now opaque register values — cannot be re-loaded

  float fs0 = FS[(d * 4 + 0) * 256 + j];
  float fs1 = FS[(d * 4 + 1) * 256 + j];
  float fs2 = FS[(d * 4 + 2) * 256 + j];
  float fs3 = FS[(d * 4 + 3) * 256 + j];

  float cst = 0.f;
  const uint2* U2 = (const uint2*)U;
  size_t ub = (size_t)d * TT * 256 + j;
  int stp = d ? -1 : 1;
  uint2 u_c = {0u, 0u}, u_n = {0u, 0u};
  if (t < 256){
    cst = c0[d * 256 + j];
    float hini = h0[d * 256 + j];
    hini = fminf(fmaxf(hini, -8.f), 8.f);
    hb[0][j] = (unsigned char)(char)(int)rintf(hini * (127.f / 8.f));
    int tA = d ? TT - 1 : 0;
    u_c = U2[ub + (size_t)tA * 256];
    u_n = U2[ub + (size_t)(tA + stp) * 256];
  }
  float hs = 8.f / 127.f;                // h-quant scale (step 0: h0 range ±8)
  __syncthreads();

  for (int s = 0; s < TT; s++){
    int par = s & 1;
    const uint4* hq = (const uint4*)(&hb[par][kh * 128]);
    H8(DECLH)
    H8(LOADH)

    int a0 = 0, a1 = 0, a2 = 0, a3 = 0;
    H8(DOTQ)                            // 128 x v_dot4_i32_i8, 4-way ILP

    float m0 = fs0 * hs, m1 = fs1 * hs, m2 = fs2 * hs, m3 = fs3 * hs;
    float4 zp;
    zp.x = (float)a0 * m0; zp.y = (float)a1 * m1;
    zp.z = (float)a2 * m2; zp.w = (float)a3 * m3;
    zl[t] = zp;
    BARRIER_LDS();

    if (t < 256){
      int tt = d ? (TT - 1 - s) : s;
      float4 zq = zl[t + 256];
      float zi = bflo(u_c.x) + zp.x + zq.x;
      float zf = bfhi(u_c.x) + zp.y + zq.y;
      float zg = bflo(u_c.y) + zp.z + zq.z;
      float zo = bfhi(u_c.y) + zp.w + zq.w;
      float gi = sigm(zi), gf = sigm(zf), go = sigm(zo), gg = tanh_fast(zg);
      cst = gf * cst + gi * gg;
      float h = go * tanh_fast(cst);
      hout[(size_t)tt * 512 + d * 256 + j] = f2bf(h);
      int q = (int)rintf(fminf(fmaxf(h, -1.f), 1.f) * 127.f);
      hb[par ^ 1][j] = (unsigned char)(char)q;
      u_c = u_n;
      int t2 = tt + 2 * stp;
      if (t2 >= 0 && t2 < TT) u_n = U2[ub + (size_t)t2 * 256];
    }
    hs = 1.f / 127.f;                   // steps >=1: h in (-1,1)
    BARRIER_LDS();
  }
}

// feats via MFMA: FE[t][j] = HOUT[t]·WOP[j] + bout[j], WOP padded to 32 rows
__global__ void k_feats2(const unsigned short* __restrict__ HOUT,
                         const unsigned short* __restrict__ WOP,
                         const float* __restrict__ bout,
                         float* __restrict__ feats){
  int wave = threadIdx.x >> 6, l = threadIdx.x & 63;
  int tile = blockIdx.x * 4 + wave;           // 0..511
  int mt = tile & 255, nt = tile >> 8;        // 256 M-tiles x 2 N-tiles
  int lm = l & 15, lq = l >> 4;
  const unsigned short* Arow = HOUT + (size_t)(mt * 16 + lm) * 512 + lq * 8;
  const unsigned short* Brow = WOP  + (size_t)(nt * 16 + lm) * 512 + lq * 8;
  v4f acc = {0.f, 0.f, 0.f, 0.f};
#pragma unroll
  for (int kb = 0; kb < 16; kb++){
    v8s a = *(const v8s*)(Arow + kb * 32);
    v8s b = *(const v8s*)(Brow + kb * 32);
    acc = __builtin_amdgcn_mfma_f32_16x16x32_bf16(a, b, acc, 0, 0, 0);
  }
  int n = nt * 16 + lm;
  if (n < LL){
    float bi = bout[n];
#pragma unroll
    for (int r4 = 0; r4 < 4; r4++){
      int t = mt * 16 + lq * 4 + r4;
      feats[t * LL + n] = acc[r4] + bi;
    }
  }
}

// V1: per-chunk max-plus matrix product
__global__ void k_vchunk(const float* __restrict__ feats, const float* __restrict__ trans,
                         float* __restrict__ P){
  int c = blockIdx.x, j = threadIdx.x;
  __shared__ float Ps[2][LL][LL];
  bool act = j < LL;
  float trow[LL];
  if (act){
#pragma unroll
    for (int i = 0; i < LL; i++) trow[i] = trans[j * LL + i];
    for (int i = 0; i < LL; i++) Ps[0][i][j] = (i == j) ? 0.f : -1e30f;
  }
  __syncthreads();
  for (int s = 0; s < 16; s++){
    int t = c * 16 + s;
    int pb = s & 1;
    if (act){
      float fj = feats[t * LL + j];
      for (int i = 0; i < LL; i++){
        float m = Ps[pb][i][0] + trow[0];
#pragma unroll
        for (int mm = 1; mm < LL; mm++) m = fmaxf(m, Ps[pb][i][mm] + trow[mm]);
        Ps[pb ^ 1][i][j] = m + fj;
      }
    }
    __syncthreads();
  }
  if (act)
    for (int i = 0; i < LL; i++) P[((size_t)c * LL + i) * LL + j] = Ps[0][i][j];
}

// V2: sequential boundary-alpha scan (prefetch-pipelined)
__global__ void k_vscan(const float* __restrict__ P, float* __restrict__ bal){
  int tid = threadIdx.x;
  bool act = tid < LL;
  __shared__ float al[LL];
  __shared__ float Pl[400];
  if (act){
    float a = (tid == STARTT) ? 0.f : NEGV;
    al[tid] = a;
    bal[tid] = a;
  }
  for (int k = tid; k < 400; k += 64) Pl[k] = P[k];
  __syncthreads();
  for (int c = 0; c < NCH; c++){
    float p0 = 0.f, p1 = 0.f, p2 = 0.f, p3 = 0.f, p4 = 0.f, p5 = 0.f, p6 = 0.f;
    if (c + 1 < NCH){
      const float* Pn = P + (size_t)(c + 1) * 400;
      p0 = Pn[tid];        p1 = Pn[tid + 64];  p2 = Pn[tid + 128];
      p3 = Pn[tid + 192];  p4 = Pn[tid + 256]; p5 = Pn[tid + 320];
      if (tid + 384 < 400) p6 = Pn[tid + 384];
    }
    float m = -1e30f;
    if (act){
      m = al[0] + Pl[tid];
#pragma unroll
      for (int i = 1; i < LL; i++) m = fmaxf(m, al[i] + Pl[i * LL + tid]);
    }
    __syncthreads();
    if (act){
      al[tid] = m;
      bal[(c + 1) * LL + tid] = m;
    }
    if (c + 1 < NCH){
      Pl[tid] = p0;        Pl[tid + 64] = p1;  Pl[tid + 128] = p2;
      Pl[tid + 192] = p3;  Pl[tid + 256] = p4; Pl[tid + 320] = p5;
      if (tid + 384 < 400) Pl[tid + 384] = p6;
    }
    __syncthreads();
  }
}

// V3: per-chunk backpointers + chunk backtrace map
__global__ void k_vbp(const float* __restrict__ feats, const float* __restrict__ trans,
                      const float* __restrict__ bal, unsigned char* __restrict__ bp,
                      unsigned char* __restrict__ M){
  int c = blockIdx.x, j = threadIdx.x;
  bool act = j < LL;
  __shared__ float al[2][LL];
  __shared__ unsigned char bpl[16][LL];
  float trow[LL];
  if (act){
#pragma unroll
    for (int i = 0; i < LL; i++) trow[i] = trans[j * LL + i];
    al[0][j] = bal[c * LL + j];
  }
  __syncthreads();
  for (int s = 0; s < 16; s++){
    int t = c * 16 + s;
    int pb = s & 1;
    if (act){
      float m = al[pb][0] + trow[0];
      int arg = 0;
#pragma unroll
      for (int i = 1; i < LL; i++){
        float v = al[pb][i] + trow[i];
        if (v > m){ m = v; arg = i; }
      }
      bpl[s][j] = (unsigned char)arg;
      bp[(size_t)t * LL + j] = (unsigned char)arg;
      al[pb ^ 1][j] = m + feats[t * LL + j];
    }
    __syncthreads();
  }
  if (act){
    int tag = j;
    for (int s = 15; s >= 0; s--) tag = bpl[s][tag];
    M[c * LL + j] = (unsigned char)tag;
  }
}

// V4: final score + chunk-boundary tag chase
__global__ void k_vtag(const float* __restrict__ bal, const float* __restrict__ trans,
                       const unsigned char* __restrict__ M, int* __restrict__ Eg,
                       float* __restrict__ out){
  int tid = threadIdx.x;
  __shared__ unsigned char Ml[NCH * LL];
  __shared__ float fin[LL];
  for (int k = tid; k < NCH * LL; k += 64) Ml[k] = M[k];
  if (tid < LL) fin[tid] = bal[NCH * LL + tid] + trans[STOPP * LL + tid];
  __syncthreads();
  if (tid == 0){
    float m = fin[0]; int arg = 0;
    for (int i = 1; i < LL; i++) if (fin[i] > m){ m = fin[i]; arg = i; }
    out[0] = m;
    int tag = arg;
    Eg[NCH - 1] = tag;
    for (int c = NCH - 1; c >= 1; c--){
      tag = Ml[c * LL + tag];
      Eg[c - 1] = tag;
    }
  }
}

// V5: parallel path emission
__global__ void k_vemit(const int* __restrict__ Eg, const unsigned char* __restrict__ bp,
                        float* __restrict__ out){
  int c = threadIdx.x;
  int tag = Eg[c];
  out[1 + c * 16 + 15] = (float)tag;
  for (int s = 15; s >= 1; s--){
    tag = bp[(size_t)(c * 16 + s) * LL + tag];
    out[1 + c * 16 + s - 1] = (float)tag;
  }
}

// ---------- launcher ----------
extern "C" void kernel_launch(void* const* d_in, const int* in_sizes, int n_in,
                              void* d_out, int out_size, void* d_ws, size_t ws_size,
                              hipStream_t stream){
  (void)in_sizes; (void)n_in; (void)out_size; (void)ws_size;
  const int*   x     = (const int*)d_in[0];
  const float* emb   = (const float*)d_in[1];
  const float* wihf  = (const float*)d_in[2];
  const float* whhf  = (const float*)d_in[3];
  const float* bihf  = (const float*)d_in[4];
  const float* bhhf  = (const float*)d_in[5];
  const float* wihb  = (const float*)d_in[6];
  const float* whhb  = (const float*)d_in[7];
  const float* bihb  = (const float*)d_in[8];
  const float* bhhb  = (const float*)d_in[9];
  const float* wout  = (const float*)d_in[10];
  const float* bout  = (const float*)d_in[11];
  const float* trans = (const float*)d_in[12];
  const float* h0    = (const float*)d_in[13];
  const float* c0    = (const float*)d_in[14];
  float* out = (float*)d_out;
  char* ws = (char*)d_ws;

  unsigned short* U    = (unsigned short*)(ws + OFF_U);
  unsigned short* X    = (unsigned short*)(ws + OFF_X);
  unsigned short* WIH  = (unsigned short*)(ws + OFF_WIH);
  float*          BIAS = (float*)(ws + OFF_BIAS);
  unsigned int*   WQ   = (unsigned int*)(ws + OFF_WQ);
  float*          FS   = (float*)(ws + OFF_FS);
  unsigned short* WOP  = (unsigned short*)(ws + OFF_WOP);
  unsigned short* HOUT = (unsigned short*)(ws + OFF_HOUT);
  float*          FE   = (float*)(ws + OFF_FE);
  float*          P    = (float*)(ws + OFF_P);
  float*          BAL  = (float*)(ws + OFF_BAL);
  unsigned char*  BP   = (unsigned char*)(ws + OFF_BP);
  unsigned char*  M    = (unsigned char*)(ws + OFF_M);
  int*            EG   = (int*)(ws + OFF_EG);

  k_gather<<<TT, 64, 0, stream>>>(x, emb, X);
  k_wih<<<256, 256, 0, stream>>>(wihf, wihb, WIH);
  k_bias<<<8, 256, 0, stream>>>(bihf, bhhf, bihb, bhhb, BIAS);
  k_wout<<<64, 256, 0, stream>>>(wout, WOP);
  k_whh4<<<2048, 64, 0, stream>>>(whhf, whhb, WQ, FS);
  k_gemm_u<<<8192, 256, 0, stream>>>(X, WIH, BIAS, U);
  k_lstm6<<<2, 512, 0, stream>>>(U, (const uint4*)WQ, FS, h0, c0, HOUT);
  k_feats2<<<128, 256, 0, stream>>>(HOUT, WOP, bout, FE);
  k_vchunk<<<NCH, 64, 0, stream>>>(FE, trans, P);
  k_vscan<<<1, 64, 0, stream>>>(P, BAL);
  k_vbp<<<NCH, 64, 0, stream>>>(FE, trans, BAL, BP, M);
  k_vtag<<<1, 64, 0, stream>>>(BAL, trans, M, EG, out);
  k_vemit<<<1, 256, 0, stream>>>(EG, BP, out);
}

// Round 7
// 4404.068 us; speedup vs baseline: 1.1929x; 1.1189x over previous
//
#include <hip/hip_runtime.h>
#include <hip/hip_bf16.h>
#include <stdint.h>

#define TT 4096
#define EE 256
#define LL 20
#define STARTT 18
#define STOPP 19
#define NEGV -10000.0f
#define NCH 256   // TT/16

typedef short v8s __attribute__((ext_vector_type(8)));
typedef float v4f __attribute__((ext_vector_type(4)));

// ---------- helpers ----------
__device__ inline float bf2f(unsigned short u){
  unsigned int x = ((unsigned int)u) << 16;
  return __builtin_bit_cast(float, x);
}
__device__ inline unsigned short f2bf(float f){
  unsigned int x = __builtin_bit_cast(unsigned int, f);
  unsigned int r = (x + 0x7FFFu + ((x >> 16) & 1u)) >> 16;
  return (unsigned short)r;
}

#if __has_builtin(__builtin_amdgcn_sdot4)
#define SDOT4(a,b,c) __builtin_amdgcn_sdot4((int)(a),(int)(b),(c),false)
#else
__device__ inline int sdot4_sw(int a, int b, int c){
  return c + (int)(char)(a)        * (int)(char)(b)
           + (int)(char)(a >> 8)   * (int)(char)(b >> 8)
           + (int)(char)(a >> 16)  * (int)(char)(b >> 16)
           + (int)(char)(a >> 24)  * (int)(char)(b >> 24);
}
#define SDOT4(a,b,c) sdot4_sw((int)(a),(int)(b),(c))
#endif

__device__ inline float tanh_fast(float x){
  x = fminf(fmaxf(x, -20.f), 20.f);
  float e = __expf(-2.f * x);
  return (1.f - e) / (1.f + e);
}
__device__ inline float sigm(float x){
  return 1.f / (1.f + __expf(-x));
}

// lgkm-only barrier: syncs LDS without draining outstanding global (vmcnt) prefetch
#define BARRIER_LDS() asm volatile("s_waitcnt lgkmcnt(0)\ns_barrier" ::: "memory")

// ---------- workspace layout (bytes) ----------
constexpr size_t OFF_U    = 0;                              // bf16 [2][T][1024] (row-major gate rows)
constexpr size_t SZ_U     = 2ull*TT*1024*2;
constexpr size_t OFF_X    = OFF_U + SZ_U;                   // bf16 [T][E]
constexpr size_t SZ_X     = (size_t)TT*EE*2;
constexpr size_t OFF_WIH  = OFF_X + SZ_X;                   // bf16 [2048][256]
constexpr size_t SZ_WIH   = 2048ull*256*2;
constexpr size_t OFF_BIAS = OFF_WIH + SZ_WIH;               // f32 [2048]
constexpr size_t SZ_BIAS  = 2048ull*4;
constexpr size_t OFF_WQ   = OFF_BIAS + SZ_BIAS;             // uint4 [2][16][1024] (i8 packed)
constexpr size_t SZ_WQ    = 2ull*16*1024*16;
constexpr size_t OFF_FS   = OFF_WQ + SZ_WQ;                 // f32 [2][1024]
constexpr size_t SZ_FS    = 2ull*1024*4;
constexpr size_t OFF_WOP  = OFF_FS + SZ_FS;                 // bf16 [32][512]
constexpr size_t SZ_WOP   = 32ull*512*2;
constexpr size_t OFF_HOUT = OFF_WOP + SZ_WOP;               // bf16 [T][512]
constexpr size_t SZ_HOUT  = (size_t)TT*512*2;
constexpr size_t OFF_FE   = OFF_HOUT + SZ_HOUT;             // f32 [T][20]
constexpr size_t SZ_FE    = (size_t)TT*LL*4;
constexpr size_t OFF_P    = OFF_FE + SZ_FE;                 // f32 [256][20][20]
constexpr size_t SZ_P     = 256ull*400*4;
constexpr size_t OFF_BAL  = OFF_P + SZ_P;                   // f32 [257][20]
constexpr size_t SZ_BAL   = 20736;
constexpr size_t OFF_BP   = OFF_BAL + SZ_BAL;               // u8 [T][20]
constexpr size_t SZ_BP    = (size_t)TT*LL;
constexpr size_t OFF_M    = OFF_BP + SZ_BP;                 // u8 [256][20]
constexpr size_t SZ_M     = 256ull*LL;
constexpr size_t OFF_EG   = OFF_M + SZ_M + 64;              // i32 [256]

// ---------- prep kernels ----------

__global__ void k_gather(const int* __restrict__ x, const float* __restrict__ emb,
                         unsigned short* __restrict__ X){
  int t = blockIdx.x;
  int xt = x[t];
  const float4* src = (const float4*)(emb + (size_t)xt * EE);
  float4 v = src[threadIdx.x];
  ushort4 o;
  o.x = f2bf(v.x); o.y = f2bf(v.y); o.z = f2bf(v.z); o.w = f2bf(v.w);
  ((ushort4*)(X + (size_t)t * EE))[threadIdx.x] = o;
}

__global__ void k_wih(const float* __restrict__ wf, const float* __restrict__ wb,
                      unsigned short* __restrict__ WIH){
  int gid = blockIdx.x * 256 + threadIdx.x;   // 65536
  int row = gid >> 5, c8 = gid & 31;
  const float* src = (row < 1024 ? wf + (size_t)row * EE : wb + (size_t)(row - 1024) * EE) + c8 * 8;
  unsigned short* dst = WIH + (size_t)row * 256 + c8 * 8;
#pragma unroll
  for (int i = 0; i < 8; i++) dst[i] = f2bf(src[i]);
}

__global__ void k_bias(const float* bf, const float* hf, const float* bb, const float* hb,
                       float* __restrict__ bias){
  int i = blockIdx.x * 256 + threadIdx.x;     // 2048
  int r = i & 1023;
  bias[i] = (i < 1024) ? (bf[r] + hf[r]) : (bb[r] + hb[r]);
}

// w_out -> bf16, padded to 32 rows
__global__ void k_wout(const float* __restrict__ wout, unsigned short* __restrict__ WOP){
  int gid = blockIdx.x * 256 + threadIdx.x;   // 16384 = 32*512
  int row = gid >> 9, k = gid & 511;
  WOP[gid] = (row < LL) ? f2bf(wout[row * 512 + k]) : 0;
}

// quantize W_hh rows to int8 with per-row scale.
// WQ uint4 layout: [(d*16 + q4)*1024 + R] = cols 16*q4..16*q4+15 of row R.
// FS: [d*1024 + R] = rowmax/127
__global__ void k_whh5(const float* __restrict__ whf, const float* __restrict__ whb,
                       unsigned int* __restrict__ WQ, float* __restrict__ FS){
  int row = blockIdx.x;       // 0..2047
  int d = row >> 10, R = row & 1023;
  const float* W = (d ? whb : whf) + (size_t)R * 256;
  int t = threadIdx.x;        // 0..63 ; covers cols 4t..4t+3
  float4 v = ((const float4*)W)[t];
  float m = fmaxf(fmaxf(fabsf(v.x), fabsf(v.y)), fmaxf(fabsf(v.z), fabsf(v.w)));
#pragma unroll
  for (int o = 32; o >= 1; o >>= 1) m = fmaxf(m, __shfl_down(m, o));
  m = __shfl(m, 0);
  float sc = (m > 0.f) ? (m / 127.f) : 1.f;
  float inv = 1.f / sc;
  int a = (int)rintf(v.x * inv), b = (int)rintf(v.y * inv);
  int c = (int)rintf(v.z * inv), e = (int)rintf(v.w * inv);
  unsigned int pack = ((unsigned)a & 255u) | (((unsigned)b & 255u) << 8)
                    | (((unsigned)c & 255u) << 16) | (((unsigned)e & 255u) << 24);
  int q4 = t >> 2, comp = t & 3;
  WQ[(((size_t)(d * 16 + q4)) * 1024 + R) * 4 + comp] = pack;
  if (t == 0) FS[d * 1024 + R] = sc;
}

// U[d][t][r] = bf16( X[t]·W_ih row r + bias )  via 16x16x32 bf16 MFMA
__global__ void k_gemm_u(const unsigned short* __restrict__ X,
                         const unsigned short* __restrict__ WIH,
                         const float* __restrict__ bias,
                         unsigned short* __restrict__ U){
  int wave = threadIdx.x >> 6, l = threadIdx.x & 63;
  int tile = blockIdx.x * 4 + wave;           // 0..32767
  int mt = tile & 255, nt = tile >> 8;        // 256 x 128 tiles
  int lm = l & 15, lq = l >> 4;
  const unsigned short* Arow = X   + (size_t)(mt * 16 + lm) * 256 + lq * 8;
  const unsigned short* Brow = WIH + (size_t)(nt * 16 + lm) * 256 + lq * 8;
  v4f acc = {0.f, 0.f, 0.f, 0.f};
#pragma unroll
  for (int kb = 0; kb < 8; kb++){
    v8s a = *(const v8s*)(Arow + kb * 32);
    v8s b = *(const v8s*)(Brow + kb * 32);
    acc = __builtin_amdgcn_mfma_f32_16x16x32_bf16(a, b, acc, 0, 0, 0);
  }
  int n = nt * 16 + lm;                       // 0..2047 gate-row
  int dd = n >> 10, r = n & 1023;
  float bi = bias[n];
#pragma unroll
  for (int r4 = 0; r4 < 4; r4++){
    int t = mt * 16 + lq * 4 + r4;
    U[((size_t)(dd * TT + t)) * 1024 + r] = f2bf(acc[r4] + bi);
  }
}

// ---------- the recurrent core ----------
// grid=2 (one CU per direction), block=1024 (16 waves, 4/SIMD pinned).
// thread t owns ONE gate row t (gate g=t>>8, elem j=t&255), full K=256:
// 64 u32 of packed-i8 weights = 64 VGPRs — small enough that the register
// allocator keeps them resident even at its conservative ~88-reg choice
// (R3-R5 failure: 128+ weight regs always spilled). h: 256 B i8 LDS double
// buffer read via broadcast ds_read_b128; z combine via 4 KB LDS zbuf.

#define Q16(M) M(0) M(1) M(2) M(3) M(4) M(5) M(6) M(7) \
               M(8) M(9) M(10) M(11) M(12) M(13) M(14) M(15)

#define DECLW(q) unsigned wx_##q, wy_##q, wz_##q, ww_##q;
#define LOADW(q) { uint4 _tw = WQ4[wbase + (q) * 1024]; \
                   wx_##q = _tw.x; wy_##q = _tw.y; wz_##q = _tw.z; ww_##q = _tw.w; }
#define PINW(q) asm volatile("" : "+v"(wx_##q), "+v"(wy_##q), "+v"(wz_##q), "+v"(ww_##q));
#define DOTQ(q) { uint4 _h = hq[q]; \
                  a = SDOT4(wx_##q, _h.x, a); a = SDOT4(wy_##q, _h.y, a); \
                  a = SDOT4(wz_##q, _h.z, a); a = SDOT4(ww_##q, _h.w, a); }

__global__ void __launch_bounds__(1024)
__attribute__((amdgpu_waves_per_eu(4, 4)))
k_lstm7(
    const unsigned short* __restrict__ U, const uint4* __restrict__ WQ4,
    const float* __restrict__ FS, const float* __restrict__ h0,
    const float* __restrict__ c0, unsigned short* __restrict__ hout){
  int d = blockIdx.x;
  int t = threadIdx.x;          // gate row within direction
  int j = t & 255;

  __shared__ __align__(16) unsigned char hb[2][256];
  __shared__ __align__(16) float zbuf[1024];

  Q16(DECLW)
  {
    size_t wbase = (size_t)d * 16 * 1024 + t;
    Q16(LOADW)
  }
  Q16(PINW)

  float fs = FS[d * 1024 + t];

  float cst = 0.f;
  if (t < 256){
    cst = c0[d * 256 + t];
    float hini = h0[d * 256 + t];
    hini = fminf(fmaxf(hini, -8.f), 8.f);
    hb[0][t] = (unsigned char)(char)(int)rintf(hini * (127.f / 8.f));
  }

  const unsigned short* Up = U + (size_t)d * TT * 1024 + t;
  int stp = d ? -1 : 1;
  int tA = d ? TT - 1 : 0;
  unsigned short u_c = Up[(size_t)tA * 1024];
  unsigned short u_n = Up[(size_t)(tA + stp) * 1024];

  float hs = 8.f / 127.f;                // h-quant scale (step 0: h0 range ±8)
  __syncthreads();

  for (int s = 0; s < TT; s++){
    int par = s & 1;
    int tt = d ? (TT - 1 - s) : s;
    const uint4* hq = (const uint4*)(&hb[par][0]);   // uniform → broadcast reads

    int a = 0;
    Q16(DOTQ)                           // 64 x v_dot4_i32_i8

    float z = bf2f(u_c) + (float)a * (fs * hs);
    zbuf[t] = z;

    // rotate u prefetch (independent of LDS barrier; vmcnt stays in flight)
    u_c = u_n;
    int t2 = tt + 2 * stp;
    if (t2 >= 0 && t2 < TT) u_n = Up[(size_t)t2 * 1024];

    BARRIER_LDS();

    if (t < 256){
      float zi = z;                     // own row = gate i, elem j=t
      float zf = zbuf[256 + t];
      float zg = zbuf[512 + t];
      float zo = zbuf[768 + t];
      float gi = sigm(zi), gf = sigm(zf), go = sigm(zo), gg = tanh_fast(zg);
      cst = gf * cst + gi * gg;
      float h = go * tanh_fast(cst);
      hout[(size_t)tt * 512 + d * 256 + t] = f2bf(h);
      int q = (int)rintf(fminf(fmaxf(h, -1.f), 1.f) * 127.f);
      hb[par ^ 1][t] = (unsigned char)(char)q;
    }
    hs = 1.f / 127.f;                   // steps >=1: h in (-1,1)
    BARRIER_LDS();
  }
}

// feats via MFMA: FE[t][j] = HOUT[t]·WOP[j] + bout[j], WOP padded to 32 rows
__global__ void k_feats2(const unsigned short* __restrict__ HOUT,
                         const unsigned short* __restrict__ WOP,
                         const float* __restrict__ bout,
                         float* __restrict__ feats){
  int wave = threadIdx.x >> 6, l = threadIdx.x & 63;
  int tile = blockIdx.x * 4 + wave;           // 0..511
  int mt = tile & 255, nt = tile >> 8;        // 256 M-tiles x 2 N-tiles
  int lm = l & 15, lq = l >> 4;
  const unsigned short* Arow = HOUT + (size_t)(mt * 16 + lm) * 512 + lq * 8;
  const unsigned short* Brow = WOP  + (size_t)(nt * 16 + lm) * 512 + lq * 8;
  v4f acc = {0.f, 0.f, 0.f, 0.f};
#pragma unroll
  for (int kb = 0; kb < 16; kb++){
    v8s a = *(const v8s*)(Arow + kb * 32);
    v8s b = *(const v8s*)(Brow + kb * 32);
    acc = __builtin_amdgcn_mfma_f32_16x16x32_bf16(a, b, acc, 0, 0, 0);
  }
  int n = nt * 16 + lm;
  if (n < LL){
    float bi = bout[n];
#pragma unroll
    for (int r4 = 0; r4 < 4; r4++){
      int t = mt * 16 + lq * 4 + r4;
      feats[t * LL + n] = acc[r4] + bi;
    }
  }
}

// V1: per-chunk max-plus matrix product
__global__ void k_vchunk(const float* __restrict__ feats, const float* __restrict__ trans,
                         float* __restrict__ P){
  int c = blockIdx.x, j = threadIdx.x;
  __shared__ float Ps[2][LL][LL];
  bool act = j < LL;
  float trow[LL];
  if (act){
#pragma unroll
    for (int i = 0; i < LL; i++) trow[i] = trans[j * LL + i];
    for (int i = 0; i < LL; i++) Ps[0][i][j] = (i == j) ? 0.f : -1e30f;
  }
  __syncthreads();
  for (int s = 0; s < 16; s++){
    int t = c * 16 + s;
    int pb = s & 1;
    if (act){
      float fj = feats[t * LL + j];
      for (int i = 0; i < LL; i++){
        float m = Ps[pb][i][0] + trow[0];
#pragma unroll
        for (int mm = 1; mm < LL; mm++) m = fmaxf(m, Ps[pb][i][mm] + trow[mm]);
        Ps[pb ^ 1][i][j] = m + fj;
      }
    }
    __syncthreads();
  }
  if (act)
    for (int i = 0; i < LL; i++) P[((size_t)c * LL + i) * LL + j] = Ps[0][i][j];
}

// V2: sequential boundary-alpha scan (prefetch-pipelined)
__global__ void k_vscan(const float* __restrict__ P, float* __restrict__ bal){
  int tid = threadIdx.x;
  bool act = tid < LL;
  __shared__ float al[LL];
  __shared__ float Pl[400];
  if (act){
    float a = (tid == STARTT) ? 0.f : NEGV;
    al[tid] = a;
    bal[tid] = a;
  }
  for (int k = tid; k < 400; k += 64) Pl[k] = P[k];
  __syncthreads();
  for (int c = 0; c < NCH; c++){
    float p0 = 0.f, p1 = 0.f, p2 = 0.f, p3 = 0.f, p4 = 0.f, p5 = 0.f, p6 = 0.f;
    if (c + 1 < NCH){
      const float* Pn = P + (size_t)(c + 1) * 400;
      p0 = Pn[tid];        p1 = Pn[tid + 64];  p2 = Pn[tid + 128];
      p3 = Pn[tid + 192];  p4 = Pn[tid + 256]; p5 = Pn[tid + 320];
      if (tid + 384 < 400) p6 = Pn[tid + 384];
    }
    float m = -1e30f;
    if (act){
      m = al[0] + Pl[tid];
#pragma unroll
      for (int i = 1; i < LL; i++) m = fmaxf(m, al[i] + Pl[i * LL + tid]);
    }
    __syncthreads();
    if (act){
      al[tid] = m;
      bal[(c + 1) * LL + tid] = m;
    }
    if (c + 1 < NCH){
      Pl[tid] = p0;        Pl[tid + 64] = p1;  Pl[tid + 128] = p2;
      Pl[tid + 192] = p3;  Pl[tid + 256] = p4; Pl[tid + 320] = p5;
      if (tid + 384 < 400) Pl[tid + 384] = p6;
    }
    __syncthreads();
  }
}

// V3: per-chunk backpointers + chunk backtrace map
__global__ void k_vbp(const float* __restrict__ feats, const float* __restrict__ trans,
                      const float* __restrict__ bal, unsigned char* __restrict__ bp,
                      unsigned char* __restrict__ M){
  int c = blockIdx.x, j = threadIdx.x;
  bool act = j < LL;
  __shared__ float al[2][LL];
  __shared__ unsigned char bpl[16][LL];
  float trow[LL];
  if (act){
#pragma unroll
    for (int i = 0; i < LL; i++) trow[i] = trans[j * LL + i];
    al[0][j] = bal[c * LL + j];
  }
  __syncthreads();
  for (int s = 0; s < 16; s++){
    int t = c * 16 + s;
    int pb = s & 1;
    if (act){
      float m = al[pb][0] + trow[0];
      int arg = 0;
#pragma unroll
      for (int i = 1; i < LL; i++){
        float v = al[pb][i] + trow[i];
        if (v > m){ m = v; arg = i; }
      }
      bpl[s][j] = (unsigned char)arg;
      bp[(size_t)t * LL + j] = (unsigned char)arg;
      al[pb ^ 1][j] = m + feats[t * LL + j];
    }
    __syncthreads();
  }
  if (act){
    int tag = j;
    for (int s = 15; s >= 0; s--) tag = bpl[s][tag];
    M[c * LL + j] = (unsigned char)tag;
  }
}

// V4: final score + chunk-boundary tag chase
__global__ void k_vtag(const float* __restrict__ bal, const float* __restrict__ trans,
                       const unsigned char* __restrict__ M, int* __restrict__ Eg,
                       float* __restrict__ out){
  int tid = threadIdx.x;
  __shared__ unsigned char Ml[NCH * LL];
  __shared__ float fin[LL];
  for (int k = tid; k < NCH * LL; k += 64) Ml[k] = M[k];
  if (tid < LL) fin[tid] = bal[NCH * LL + tid] + trans[STOPP * LL + tid];
  __syncthreads();
  if (tid == 0){
    float m = fin[0]; int arg = 0;
    for (int i = 1; i < LL; i++) if (fin[i] > m){ m = fin[i]; arg = i; }
    out[0] = m;
    int tag = arg;
    Eg[NCH - 1] = tag;
    for (int c = NCH - 1; c >= 1; c--){
      tag = Ml[c * LL + tag];
      Eg[c - 1] = tag;
    }
  }
}

// V5: parallel path emission
__global__ void k_vemit(const int* __restrict__ Eg, const unsigned char* __restrict__ bp,
                        float* __restrict__ out){
  int c = threadIdx.x;
  int tag = Eg[c];
  out[1 + c * 16 + 15] = (float)tag;
  for (int s = 15; s >= 1; s--){
    tag = bp[(size_t)(c * 16 + s) * LL + tag];
    out[1 + c * 16 + s - 1] = (float)tag;
  }
}

// ---------- launcher ----------
extern "C" void kernel_launch(void* const* d_in, const int* in_sizes, int n_in,
                              void* d_out, int out_size, void* d_ws, size_t ws_size,
                              hipStream_t stream){
  (void)in_sizes; (void)n_in; (void)out_size; (void)ws_size;
  const int*   x     = (const int*)d_in[0];
  const float* emb   = (const float*)d_in[1];
  const float* wihf  = (const float*)d_in[2];
  const float* whhf  = (const float*)d_in[3];
  const float* bihf  = (const float*)d_in[4];
  const float* bhhf  = (const float*)d_in[5];
  const float* wihb  = (const float*)d_in[6];
  const float* whhb  = (const float*)d_in[7];
  const float* bihb  = (const float*)d_in[8];
  const float* bhhb  = (const float*)d_in[9];
  const float* wout  = (const float*)d_in[10];
  const float* bout  = (const float*)d_in[11];
  const float* trans = (const float*)d_in[12];
  const float* h0    = (const float*)d_in[13];
  const float* c0    = (const float*)d_in[14];
  float* out = (float*)d_out;
  char* ws = (char*)d_ws;

  unsigned short* U    = (unsigned short*)(ws + OFF_U);
  unsigned short* X    = (unsigned short*)(ws + OFF_X);
  unsigned short* WIH  = (unsigned short*)(ws + OFF_WIH);
  float*          BIAS = (float*)(ws + OFF_BIAS);
  unsigned int*   WQ   = (unsigned int*)(ws + OFF_WQ);
  float*          FS   = (float*)(ws + OFF_FS);
  unsigned short* WOP  = (unsigned short*)(ws + OFF_WOP);
  unsigned short* HOUT = (unsigned short*)(ws + OFF_HOUT);
  float*          FE   = (float*)(ws + OFF_FE);
  float*          P    = (float*)(ws + OFF_P);
  float*          BAL  = (float*)(ws + OFF_BAL);
  unsigned char*  BP   = (unsigned char*)(ws + OFF_BP);
  unsigned char*  M    = (unsigned char*)(ws + OFF_M);
  int*            EG   = (int*)(ws + OFF_EG);

  k_gather<<<TT, 64, 0, stream>>>(x, emb, X);
  k_wih<<<256, 256, 0, stream>>>(wihf, wihb, WIH);
  k_bias<<<8, 256, 0, stream>>>(bihf, bhhf, bihb, bhhb, BIAS);
  k_wout<<<64, 256, 0, stream>>>(wout, WOP);
  k_whh5<<<2048, 64, 0, stream>>>(whhf, whhb, WQ, FS);
  k_gemm_u<<<8192, 256, 0, stream>>>(X, WIH, BIAS, U);
  k_lstm7<<<2, 1024, 0, stream>>>(U, (const uint4*)WQ, FS, h0, c0, HOUT);
  k_feats2<<<128, 256, 0, stream>>>(HOUT, WOP, bout, FE);
  k_vchunk<<<NCH, 64, 0, stream>>>(FE, trans, P);
  k_vscan<<<1, 64, 0, stream>>>(P, BAL);
  k_vbp<<<NCH, 64, 0, stream>>>(FE, trans, BAL, BP, M);
  k_vtag<<<1, 64, 0, stream>>>(BAL, trans, M, EG, out);
  k_vemit<<<1, 256, 0, stream>>>(EG, BP, out);
}